// Round 4
// baseline (364.606 us; speedup 1.0000x reference)
//
#include <hip/hip_runtime.h>
#include <hip/hip_bf16.h>
#include <cstdint>

typedef _Float16 half_t;
typedef _Float16 f16x8 __attribute__((ext_vector_type(8), aligned(16)));
typedef _Float16 f16x4 __attribute__((ext_vector_type(4), aligned(8)));
typedef _Float16 f16x2 __attribute__((ext_vector_type(2), aligned(4)));
typedef float f32x4 __attribute__((ext_vector_type(4)));

#define B_ 128
#define C_ 2048
#define N_ 196
#define S_ 312
#define L_ 300
#define M_ 1024
#define NP 224   // padded N (14 x 16)
#define SP 384   // padded S for prep GEMMs (3 x 128)

// ---- async global->LDS, 16B per lane ----
__device__ __forceinline__ void gload16(const half_t* g, half_t* l) {
    __builtin_amdgcn_global_load_lds((const __attribute__((address_space(1))) void*)g,
                                     (__attribute__((address_space(3))) void*)l, 16, 0, 0);
}

// ---------------------------------------------------------------------------
// q[s][m] = sum_l att[s][l]*Wq[m][l] + bq[m] -> fp16 [384][1024], zero pad (f32 accum path)
// grid (16 mc, 48 sc), block 256
__global__ __launch_bounds__(256) void k_q(const float* __restrict__ att, const float* __restrict__ Wq,
                                           const float* __restrict__ bq, half_t* __restrict__ qh) {
    int mc = blockIdx.x, sc = blockIdx.y;
    int s0 = sc * 8;
    __shared__ float als[8][L_];
    int t = threadIdx.x;
    for (int idx = t; idx < 8 * L_; idx += 256) {
        int si = idx / L_, li = idx % L_;
        als[si][li] = (s0 + si < S_) ? att[(size_t)(s0 + si) * L_ + li] : 0.f;
    }
    __syncthreads();
    int wid = t >> 6, lane = t & 63;
    for (int mi = 0; mi < 16; ++mi) {
        int m = mc * 64 + wid * 16 + mi;
        float acc[8] = {0, 0, 0, 0, 0, 0, 0, 0};
        for (int r = 0; r < 5; ++r) {
            int li = lane + 64 * r;
            if (li < L_) {
                float wv = Wq[(size_t)m * L_ + li];
#pragma unroll
                for (int k = 0; k < 8; ++k) acc[k] += als[k][li] * wv;
            }
        }
#pragma unroll
        for (int k = 0; k < 8; ++k) {
            float v = acc[k];
            for (int off = 32; off; off >>= 1) v += __shfl_xor(v, off);
            if (lane == 0) {
                int s = s0 + k;
                float res = (s < S_) ? (v + bq[m]) : 0.f;
                qh[(size_t)s * M_ + m] = (half_t)res;
            }
        }
    }
}

// ---------------------------------------------------------------------------
// V_final f32 [312][2048] -> f16 [384][2048] zero-padded. grid 768, block 256
__global__ __launch_bounds__(256) void k_vconv(const float* __restrict__ V, half_t* __restrict__ Vh) {
    size_t e = ((size_t)blockIdx.x * 256 + threadIdx.x) * 4;
    int s = (int)(e / C_);
    float4 v = {0, 0, 0, 0};
    if (s < S_) v = *(const float4*)&V[e];
    f16x4 h; h[0] = (half_t)v.x; h[1] = (half_t)v.y; h[2] = (half_t)v.z; h[3] = (half_t)v.w;
    *(f16x4*)&Vh[e] = h;
}

// ---------------------------------------------------------------------------
// Three transposes (f32 [R][Cc] -> f16 [Cc][R]) in one dispatch.
// z=0: Wk 1024x2048; z=1: Wo 2048x1024; z=2: Wv 1024x2048.  grid (32,32,3), block 256
__global__ __launch_bounds__(256) void k_transp3(const float* __restrict__ Wk, const float* __restrict__ Wo,
                                                 const float* __restrict__ Wv, half_t* __restrict__ WkT,
                                                 half_t* __restrict__ WoT, half_t* __restrict__ WvT) {
    __shared__ __attribute__((aligned(16))) half_t lsT[64][72];
    int z = blockIdx.z;
    const float* in; half_t* out; int R, Cc;
    if (z == 0)      { in = Wk; out = WkT; R = 1024; Cc = 2048; }
    else if (z == 1) { in = Wo; out = WoT; R = 2048; Cc = 1024; }
    else             { in = Wv; out = WvT; R = 1024; Cc = 2048; }
    if ((int)blockIdx.x >= Cc / 64 || (int)blockIdx.y >= R / 64) return;
    int c0 = blockIdx.x * 64, r0 = blockIdx.y * 64;
    int t = threadIdx.x;
#pragma unroll
    for (int i = 0; i < 4; ++i) {
        int Q = t + 256 * i;
        int rq = Q >> 5, cq = Q & 31;
        int rr = 2 * rq, cc = 2 * cq;
        const float* p0 = in + (size_t)(r0 + rr) * Cc + c0 + cc;
        float2 va = *(const float2*)p0;
        float2 vb = *(const float2*)(p0 + Cc);
        f16x2 w0; w0[0] = (half_t)va.x; w0[1] = (half_t)vb.x;
        f16x2 w1; w1[0] = (half_t)va.y; w1[1] = (half_t)vb.y;
        *(f16x2*)&lsT[cc][rr]     = w0;   // lsT[c][r] = in[r][c]
        *(f16x2*)&lsT[cc + 1][rr] = w1;
    }
    __syncthreads();
    int cl = t >> 2, ch = t & 3;
    f16x8 v0 = *(const f16x8*)&lsT[cl][ch * 16];
    f16x8 v1 = *(const f16x8*)&lsT[cl][ch * 16 + 8];
    half_t* po = out + (size_t)(c0 + cl) * R + r0 + ch * 16;
    *(f16x8*)po = v0;
    *(f16x8*)(po + 8) = v1;
}

// ---------------------------------------------------------------------------
// Counted-vmcnt 3-slot-ring fp16 MFMA GEMM: C[r][col] = sum_k A[r][k] * Bm[col][k]
// A: [gridDim.y*128][kdim], Bm: [gridDim.x*128][kdim], f16 row-major, kdim % 32 == 0, kdim/32 >= 2.
// MODE 0: outF (f32) all rows.  MODE 1: outH (f16), rows < 320 only.  MODE 2: both, all rows.
template <int MODE>
__global__ __launch_bounds__(256) void k_gemm(const half_t* __restrict__ A, const half_t* __restrict__ Bm,
                                              int kdim, float* __restrict__ outF, half_t* __restrict__ outH,
                                              int ldo) {
    __shared__ __attribute__((aligned(16))) half_t lsA[3][128 * 32];
    __shared__ __attribute__((aligned(16))) half_t lsB[3][128 * 32];
    int t = threadIdx.x;
    int wid = t >> 6, lane = t & 63;
    const int rA0 = blockIdx.y * 128, rB0 = blockIdx.x * 128;
    int wr = wid >> 1, wc = wid & 1;
    int g = lane >> 4, l15 = lane & 15;
    const int r_ = t >> 2, kk_ = (t & 3) * 8;
    const half_t* pA  = A + (size_t)(rA0 + r_) * kdim + kk_;
    const half_t* pA2 = pA + (size_t)64 * kdim;
    const half_t* pB  = Bm + (size_t)(rB0 + r_) * kdim + kk_;
    const half_t* pB2 = pB + (size_t)64 * kdim;
    const int lo = r_ * 32 + kk_;
    f32x4 acc[4][4] = {};
    int nk = kdim >> 5;

    // stage K-tile kc into ring slot: 4 x gload16 per thread (A 8KB + B 8KB per block)
#define STAGE(slot, kc)                              \
    do {                                             \
        gload16(pA + (kc), &lsA[slot][lo]);          \
        gload16(pA2 + (kc), &lsA[slot][lo + 2048]);  \
        gload16(pB + (kc), &lsB[slot][lo]);          \
        gload16(pB2 + (kc), &lsB[slot][lo + 2048]);  \
    } while (0)

    STAGE(0, 0);
    STAGE(1, 32);
    int cur = 0, nxt = 2;
    for (int tk = 0; tk < nk; ++tk) {
        // wait for stage tk only: leave the newest stage (4 ops) in flight
        if (tk == nk - 1) asm volatile("s_waitcnt vmcnt(0)" ::: "memory");
        else              asm volatile("s_waitcnt vmcnt(4)" ::: "memory");
        __builtin_amdgcn_s_barrier();   // all threads' stage tk landed; prior reads of slot nxt done
        __builtin_amdgcn_sched_barrier(0);  // pin: no ds_read/STAGE may cross the barrier
        f16x8 af[4], bf[4];
#pragma unroll
        for (int i = 0; i < 4; ++i) af[i] = *(const f16x8*)&lsA[cur][(wr * 64 + i * 16 + l15) * 32 + g * 8];
#pragma unroll
        for (int j = 0; j < 4; ++j) bf[j] = *(const f16x8*)&lsB[cur][(wc * 64 + j * 16 + l15) * 32 + g * 8];
        if (tk + 2 < nk) STAGE(nxt, (tk + 2) * 32);  // depth-2 prefetch, lands ~2 iters later
#pragma unroll
        for (int i = 0; i < 4; ++i)
#pragma unroll
            for (int j = 0; j < 4; ++j)
                acc[i][j] = __builtin_amdgcn_mfma_f32_16x16x32_f16(af[i], bf[j], acc[i][j], 0, 0, 0);
        cur = (cur == 2) ? 0 : cur + 1;
        nxt = (nxt == 2) ? 0 : nxt + 1;
    }
#undef STAGE

#pragma unroll
    for (int i = 0; i < 4; ++i) {
        int r0 = rA0 + wr * 64 + i * 16 + g * 4;
#pragma unroll
        for (int j = 0; j < 4; ++j) {
            int c0 = rB0 + wc * 64 + j * 16 + l15;
#pragma unroll
            for (int qq = 0; qq < 4; ++qq) {
                int r = r0 + qq;
                float val = acc[i][j][qq];
                if (MODE == 0) {
                    outF[(size_t)r * ldo + c0] = val;
                } else if (MODE == 1) {
                    if (r < 320) outH[(size_t)r * ldo + c0] = (half_t)val;
                } else {
                    outF[(size_t)r * ldo + c0] = val;
                    outH[(size_t)r * ldo + c0] = (half_t)val;
                }
            }
        }
    }
}

// ---------------------------------------------------------------------------
// feat [nB][2048][196] f32 -> featT [(bb*224 + n)][2048] f16 (n zero-padded to 224)
// PLUS fused pool partials: poolp[(nT*B_ + bb)*C_ + c] = sum over this block's n of feat[b][c][n]
// grid (4 nT, 32 cT, nB), block 256
__global__ __launch_bounds__(256) void k_transf(const float* __restrict__ feat, half_t* __restrict__ featT,
                                                float* __restrict__ poolp) {
    __shared__ __attribute__((aligned(16))) half_t lsT[64][72];
    __shared__ float poolLs[64];
    int nT = blockIdx.x, cT = blockIdx.y, bb = blockIdx.z;
    int n0 = nT * 64, c0 = cT * 64;
    const float* fb = feat + (size_t)bb * C_ * N_;
    int t = threadIdx.x;
#pragma unroll
    for (int i = 0; i < 4; ++i) {
        int Q = t + 256 * i;
        int cq = Q >> 5, nq = Q & 31;
        int cc = 2 * cq, nn = 2 * nq;
        int n = n0 + nn;
        float2 va = {0, 0}, vb = {0, 0};
        if (n < N_) {
            const float* p0 = fb + (size_t)(c0 + cc) * N_ + n;
            va = *(const float2*)p0;
            vb = *(const float2*)(p0 + N_);
        }
        f16x2 w0; w0[0] = (half_t)va.x; w0[1] = (half_t)vb.x;
        f16x2 w1; w1[0] = (half_t)va.y; w1[1] = (half_t)vb.y;
        *(f16x2*)&lsT[nn][cc]     = w0;   // lsT[n][c]
        *(f16x2*)&lsT[nn + 1][cc] = w1;
        float sA = va.x + va.y, sB = vb.x + vb.y;
        for (int off = 16; off; off >>= 1) { sA += __shfl_xor(sA, off); sB += __shfl_xor(sB, off); }
        if ((t & 31) == 0) { poolLs[cc] = sA; poolLs[cc + 1] = sB; }
    }
    __syncthreads();
    int nl = t >> 2, ch = t & 3;
    int n = n0 + nl;
    if (n < NP) {   // rows [224,256) of nT=3 must NOT spill into the next batch's tile
        f16x8 v0 = *(const f16x8*)&lsT[nl][ch * 16];
        f16x8 v1 = *(const f16x8*)&lsT[nl][ch * 16 + 8];
        half_t* po = featT + ((size_t)bb * NP + n) * C_ + c0 + ch * 16;
        *(f16x8*)po = v0;
        *(f16x8*)(po + 8) = v1;
    }
    if (t < 64) poolp[((size_t)nT * B_ + bb) * C_ + c0 + t] = poolLs[t];
}

// ---------------------------------------------------------------------------
// base[b][s] = sum_c (mean_pool[b][c] + bo[c]) * V[s][c].  grid (4 sc, nB b), block 256
__global__ __launch_bounds__(256) void k_poolv(const float* __restrict__ poolp, const float* __restrict__ bo,
                                               const float* __restrict__ V, float* __restrict__ base) {
    int sc = blockIdx.x, b = blockIdx.y;
    __shared__ float w[C_];
    int t = threadIdx.x;
    for (int i = t; i < C_; i += 256) {
        float s = poolp[(size_t)b * C_ + i] + poolp[((size_t)B_ + b) * C_ + i] +
                  poolp[((size_t)2 * B_ + b) * C_ + i] + poolp[((size_t)3 * B_ + b) * C_ + i];
        w[i] = s * (1.0f / 196.0f) + bo[i];
    }
    __syncthreads();
    int wid = t >> 6, lane = t & 63;
    for (int s = sc * 78 + wid; s < sc * 78 + 78; s += 4) {
        const float* vr = V + (size_t)s * C_;
        float acc = 0;
#pragma unroll
        for (int i = 0; i < 32; ++i) acc += w[lane + 64 * i] * vr[lane + 64 * i];
        for (int off = 32; off; off >>= 1) acc += __shfl_xor(acc, off);
        if (lane == 0) base[(size_t)b * S_ + s] = acc;
    }
}

// ---------------------------------------------------------------------------
// ubv[s] = sum_m U[s][m]*bv[m].  grid 78, block 256 (wave per s)
__global__ __launch_bounds__(256) void k_ubv(const float* __restrict__ U, const float* __restrict__ bv,
                                             float* __restrict__ ubv) {
    int s = blockIdx.x * 4 + (threadIdx.x >> 6);
    int lane = threadIdx.x & 63;
    if (s >= S_) return;
    const float* ur = U + (size_t)s * M_;
    float acc = 0;
#pragma unroll
    for (int i = 0; i < 16; ++i) acc += ur[lane + 64 * i] * bv[lane + 64 * i];
    for (int off = 32; off; off >>= 1) acc += __shfl_xor(acc, off);
    if (lane == 0) ubv[s] = acc;
}

// ---------------------------------------------------------------------------
// softmax over n + dot: out[b][s] = base + ubv + sum_n softmax(scores)_n * W2_n
// Cm rows 0..311 = scores, rows 320..631 = W2; cols = bb*224 + n.  grid nB*78, block 256
__global__ __launch_bounds__(256) void k_reduce(const float* __restrict__ Cm, int ncols,
                                                const float* __restrict__ base, const float* __restrict__ ubv,
                                                float* __restrict__ out, int b0) {
    int w = blockIdx.x * 4 + (threadIdx.x >> 6);
    int lane = threadIdx.x & 63;
    int bb = w / S_, s = w % S_;
    const float* rs = Cm + (size_t)s * ncols + bb * NP;
    const float* rw = Cm + (size_t)(320 + s) * ncols + bb * NP;
    f32x4 sv = {0, 0, 0, 0}, wv = {0, 0, 0, 0};
    int j0 = lane * 4;
    if (j0 < N_) {
        sv = *(const f32x4*)(rs + j0);
        wv = *(const f32x4*)(rw + j0);
    }
    float m = -3.0e38f;
#pragma unroll
    for (int e = 0; e < 4; ++e)
        if (j0 + e < N_) m = fmaxf(m, sv[e]);
    for (int off = 32; off; off >>= 1) m = fmaxf(m, __shfl_xor(m, off));
    float ls = 0, dot = 0;
#pragma unroll
    for (int e = 0; e < 4; ++e) {
        if (j0 + e < N_) {
            float p = __expf(sv[e] - m);
            ls += p;
            dot += p * wv[e];
        }
    }
    for (int off = 32; off; off >>= 1) {
        ls += __shfl_xor(ls, off);
        dot += __shfl_xor(dot, off);
    }
    if (lane == 0) {
        int bg = b0 + bb;
        out[(size_t)bg * S_ + s] = base[(size_t)bg * S_ + s] + ubv[s] + dot / ls;
    }
}

// ---------------------------------------------------------------------------
extern "C" void kernel_launch(void* const* d_in, const int* in_sizes, int n_in,
                              void* d_out, int out_size, void* d_ws, size_t ws_size,
                              hipStream_t stream) {
    const float* feat = (const float*)d_in[0];
    const float* att  = (const float*)d_in[1];
    const float* Wq   = (const float*)d_in[2];
    const float* bq   = (const float*)d_in[3];
    const float* Wk   = (const float*)d_in[4];
    /* bk = d_in[5] — per-s constant over n in scores: softmax-invariant, dropped */
    const float* Wv   = (const float*)d_in[6];
    const float* bv   = (const float*)d_in[7];
    const float* Wo   = (const float*)d_in[8];
    const float* bo   = (const float*)d_in[9];
    const float* V    = (const float*)d_in[10];
    float* out = (float*)d_out;

    auto AL = [](size_t x) { return (x + 255) & ~(size_t)255; };
    const size_t szAstack = (size_t)640 * C_ * 2;
    const size_t szQh   = (size_t)SP * M_ * 2;
    const size_t szVh   = (size_t)SP * C_ * 2;
    const size_t szUf   = (size_t)SP * M_ * 4;
    const size_t szUh   = (size_t)SP * M_ * 2;
    const size_t szWT   = (size_t)C_ * M_ * 2;
    const size_t szPoolp = (size_t)4 * B_ * C_ * 4;
    const size_t szBase = (size_t)B_ * S_ * 4;
    const size_t szUbv  = (size_t)S_ * 4;
    size_t fixed = AL(szAstack) + AL(szQh) + AL(szVh) + AL(szUf) + AL(szUh) + 3 * AL(szWT) +
                   AL(szPoolp) + AL(szBase) + AL(szUbv);

    int nsplit = 1;
    while (nsplit < 32) {
        size_t nB = B_ / nsplit;
        size_t need = fixed + AL(nB * NP * C_ * 2) + AL((size_t)640 * nB * NP * 4);
        if (need <= ws_size) break;
        nsplit *= 2;
    }
    int nB = B_ / nsplit;

    char* p = (char*)d_ws;
    half_t* Astack = (half_t*)p; p += AL(szAstack);
    half_t* qh     = (half_t*)p; p += AL(szQh);
    half_t* Vh     = (half_t*)p; p += AL(szVh);
    float*  Uf     = (float*)p;  p += AL(szUf);
    half_t* Uh     = (half_t*)p; p += AL(szUh);
    half_t* WkT    = (half_t*)p; p += AL(szWT);
    half_t* WoT    = (half_t*)p; p += AL(szWT);
    half_t* WvT    = (half_t*)p; p += AL(szWT);
    float*  poolp  = (float*)p;  p += AL(szPoolp);
    float*  base   = (float*)p;  p += AL(szBase);
    float*  ubv    = (float*)p;  p += AL(szUbv);
    half_t* featT  = (half_t*)p; p += AL((size_t)nB * NP * C_ * 2);
    float*  Cbuf   = (float*)p;

    // ---- batch-independent precompute ----
    k_q<<<dim3(16, 48), 256, 0, stream>>>(att, Wq, bq, qh);
    k_vconv<<<dim3(768), 256, 0, stream>>>(V, Vh);
    k_transp3<<<dim3(32, 32, 3), 256, 0, stream>>>(Wk, Wo, Wv, WkT, WoT, WvT);
    // Qk = q @ Wk -> Astack rows 0..319
    k_gemm<1><<<dim3(16, 3), 256, 0, stream>>>(qh, WkT, M_, nullptr, Astack, C_);
    // U = V @ Wo -> Uf (f32) + Uh (f16)
    k_gemm<2><<<dim3(8, 3), 256, 0, stream>>>(Vh, WoT, C_, Uf, Uh, M_);
    k_ubv<<<dim3(78), 256, 0, stream>>>(Uf, bv, ubv);
    // Wv2 = U @ Wv -> Astack rows 320..639
    k_gemm<1><<<dim3(16, 3), 256, 0, stream>>>(Uh, WvT, M_, nullptr, Astack + (size_t)320 * C_, C_);

    // ---- main per-batch-split pipeline ----
    for (int h = 0; h < nsplit; ++h) {
        const float* fh = feat + (size_t)h * nB * C_ * N_;
        k_transf<<<dim3(4, 32, nB), 256, 0, stream>>>(fh, featT, poolp);
        k_poolv<<<dim3(4, nB), 256, 0, stream>>>(poolp, bo, V, base + (size_t)h * nB * S_);
        int ncols = nB * NP;
        k_gemm<0><<<dim3(ncols / 128, 5), 256, 0, stream>>>(Astack, featT, C_, Cbuf, nullptr, ncols);
        k_reduce<<<dim3(nB * 78), 256, 0, stream>>>(Cbuf, ncols, base, ubv, out, h * nB);
    }
}

// Round 5
// 304.154 us; speedup vs baseline: 1.1988x; 1.1988x over previous
//
#include <hip/hip_runtime.h>
#include <hip/hip_bf16.h>
#include <cstdint>

typedef _Float16 half_t;
typedef _Float16 f16x8 __attribute__((ext_vector_type(8), aligned(16)));
typedef _Float16 f16x4 __attribute__((ext_vector_type(4), aligned(8)));
typedef _Float16 f16x2 __attribute__((ext_vector_type(2), aligned(4)));
typedef float f32x4 __attribute__((ext_vector_type(4)));

#define B_ 128
#define C_ 2048
#define N_ 196
#define S_ 312
#define L_ 300
#define LP 320   // padded L (10 x 32)
#define M_ 1024
#define NP 224   // padded N (14 x 16)
#define SP 384   // padded S for prep GEMMs (3 x 128)

// ---- async global->LDS, 16B per lane ----
__device__ __forceinline__ void gload16(const half_t* g, half_t* l) {
    __builtin_amdgcn_global_load_lds((const __attribute__((address_space(1))) void*)g,
                                     (__attribute__((address_space(3))) void*)l, 16, 0, 0);
}

// ---------------------------------------------------------------------------
// f32->f16 pad/convert: att [312,300]->[384,320], Wq [1024,300]->[1024,320],
// V_final [312,2048]->[384,2048].  grid (768,1,3), block 256
__global__ __launch_bounds__(256) void k_convert(const float* __restrict__ att, const float* __restrict__ Wq,
                                                 const float* __restrict__ V, half_t* __restrict__ atth,
                                                 half_t* __restrict__ wqh, half_t* __restrict__ vh) {
    int z = blockIdx.z;
    size_t e = ((size_t)blockIdx.x * 256 + threadIdx.x) * 4;
    if (z == 0) {
        if (e >= (size_t)SP * LP) return;
        int r = (int)(e / LP), c = (int)(e % LP);
        f16x4 h;
#pragma unroll
        for (int j = 0; j < 4; ++j) h[j] = (half_t)((r < S_ && c + j < L_) ? att[(size_t)r * L_ + c + j] : 0.f);
        *(f16x4*)&atth[e] = h;
    } else if (z == 1) {
        if (e >= (size_t)M_ * LP) return;
        int r = (int)(e / LP), c = (int)(e % LP);
        f16x4 h;
#pragma unroll
        for (int j = 0; j < 4; ++j) h[j] = (half_t)((c + j < L_) ? Wq[(size_t)r * L_ + c + j] : 0.f);
        *(f16x4*)&wqh[e] = h;
    } else {
        if (e >= (size_t)SP * C_) return;
        int r = (int)(e / C_);
        f16x4 h;
        if (r < S_) {
            float4 v = *(const float4*)&V[e];
            h[0] = (half_t)v.x; h[1] = (half_t)v.y; h[2] = (half_t)v.z; h[3] = (half_t)v.w;
        } else {
            h[0] = h[1] = h[2] = h[3] = (half_t)0.f;
        }
        *(f16x4*)&vh[e] = h;
    }
}

// ---------------------------------------------------------------------------
// Three transposes (f32 [R][Cc] -> f16 [Cc][R]) in one dispatch.
// z=0: Wk 1024x2048; z=1: Wo 2048x1024; z=2: Wv 1024x2048.  grid (32,32,3), block 256
__global__ __launch_bounds__(256) void k_transp3(const float* __restrict__ Wk, const float* __restrict__ Wo,
                                                 const float* __restrict__ Wv, half_t* __restrict__ WkT,
                                                 half_t* __restrict__ WoT, half_t* __restrict__ WvT) {
    __shared__ __attribute__((aligned(16))) half_t lsT[64][72];
    int z = blockIdx.z;
    const float* in; half_t* out; int R, Cc;
    if (z == 0)      { in = Wk; out = WkT; R = 1024; Cc = 2048; }
    else if (z == 1) { in = Wo; out = WoT; R = 2048; Cc = 1024; }
    else             { in = Wv; out = WvT; R = 1024; Cc = 2048; }
    if ((int)blockIdx.x >= Cc / 64 || (int)blockIdx.y >= R / 64) return;
    int c0 = blockIdx.x * 64, r0 = blockIdx.y * 64;
    int t = threadIdx.x;
#pragma unroll
    for (int i = 0; i < 4; ++i) {
        int Q = t + 256 * i;
        int rq = Q >> 5, cq = Q & 31;
        int rr = 2 * rq, cc = 2 * cq;
        const float* p0 = in + (size_t)(r0 + rr) * Cc + c0 + cc;
        float2 va = *(const float2*)p0;
        float2 vb = *(const float2*)(p0 + Cc);
        f16x2 w0; w0[0] = (half_t)va.x; w0[1] = (half_t)vb.x;
        f16x2 w1; w1[0] = (half_t)va.y; w1[1] = (half_t)vb.y;
        *(f16x2*)&lsT[cc][rr]     = w0;   // lsT[c][r] = in[r][c]
        *(f16x2*)&lsT[cc + 1][rr] = w1;
    }
    __syncthreads();
    int cl = t >> 2, ch = t & 3;
    f16x8 v0 = *(const f16x8*)&lsT[cl][ch * 16];
    f16x8 v1 = *(const f16x8*)&lsT[cl][ch * 16 + 8];
    half_t* po = out + (size_t)(c0 + cl) * R + r0 + ch * 16;
    *(f16x8*)po = v0;
    *(f16x8*)(po + 8) = v1;
}

// ---------------------------------------------------------------------------
// Dual-descriptor prep GEMM (counted-vmcnt ring + XOR-swizzled LDS).
// C[r][col] = sum_k A[r][k] * Bm[col][k]; out row = r*rowmul + rowoff.
struct GDesc {
    const half_t* A; const half_t* Bm;
    float* outF; half_t* outH; const float* bias;
    int kdim; int ldo; int rowmul; int rowoff;
};

__global__ __launch_bounds__(256) void k_prep(GDesc d0, GDesc d1) {
    GDesc d = blockIdx.z ? d1 : d0;
    __shared__ __attribute__((aligned(16))) half_t lsA[3][128 * 32];
    __shared__ __attribute__((aligned(16))) half_t lsB[3][128 * 32];
    int t = threadIdx.x;
    int wid = t >> 6, lane = t & 63;
    const int rA0 = blockIdx.y * 128, rB0 = blockIdx.x * 128;
    int wr = wid >> 1, wc = wid & 1;
    int g = lane >> 4, l15 = lane & 15;
    const int r_ = t >> 2;
    const int gsrc = ((t & 3) ^ ((t >> 3) & 3)) * 8;  // pre-swizzled source chunk
    const int kdim = d.kdim;
    const half_t* pA  = d.A + (size_t)(rA0 + r_) * kdim + gsrc;
    const half_t* pA2 = pA + (size_t)64 * kdim;
    const half_t* pB  = d.Bm + (size_t)(rB0 + r_) * kdim + gsrc;
    const half_t* pB2 = pB + (size_t)64 * kdim;
    const int lo = t * 8;                       // linear LDS dest (chunk id = t)
    const int xsw = ((l15 >> 1) & 3) * 8;       // read-side swizzle (involution)
    f32x4 acc[4][4] = {};
    int nk = kdim >> 5;

#define STAGE(slot, kc)                              \
    do {                                             \
        gload16(pA + (kc), &lsA[slot][lo]);          \
        gload16(pA2 + (kc), &lsA[slot][lo + 2048]);  \
        gload16(pB + (kc), &lsB[slot][lo]);          \
        gload16(pB2 + (kc), &lsB[slot][lo + 2048]);  \
    } while (0)

    STAGE(0, 0);
    STAGE(1, 32);
    int cur = 0, nxt = 2;
    for (int tk = 0; tk < nk; ++tk) {
        if (tk == nk - 1) asm volatile("s_waitcnt vmcnt(0)" ::: "memory");
        else              asm volatile("s_waitcnt vmcnt(4)" ::: "memory");
        __builtin_amdgcn_s_barrier();
        __builtin_amdgcn_sched_barrier(0);
        f16x8 af[4], bf[4];
#pragma unroll
        for (int i = 0; i < 4; ++i) af[i] = *(const f16x8*)&lsA[cur][(wr * 64 + i * 16 + l15) * 32 + ((g * 8) ^ xsw)];
#pragma unroll
        for (int j = 0; j < 4; ++j) bf[j] = *(const f16x8*)&lsB[cur][(wc * 64 + j * 16 + l15) * 32 + ((g * 8) ^ xsw)];
        if (tk + 2 < nk) STAGE(nxt, (tk + 2) * 32);
#pragma unroll
        for (int i = 0; i < 4; ++i)
#pragma unroll
            for (int j = 0; j < 4; ++j)
                acc[i][j] = __builtin_amdgcn_mfma_f32_16x16x32_f16(af[i], bf[j], acc[i][j], 0, 0, 0);
        cur = (cur == 2) ? 0 : cur + 1;
        nxt = (nxt == 2) ? 0 : nxt + 1;
    }
#undef STAGE

#pragma unroll
    for (int i = 0; i < 4; ++i) {
        int r0 = rA0 + wr * 64 + i * 16 + g * 4;
#pragma unroll
        for (int j = 0; j < 4; ++j) {
            int c0 = rB0 + wc * 64 + j * 16 + l15;
            float bval = d.bias ? d.bias[c0] : 0.f;
#pragma unroll
            for (int qq = 0; qq < 4; ++qq) {
                int rr = (r0 + qq) * d.rowmul + d.rowoff;
                float val = acc[i][j][qq];
                if (d.outF) d.outF[(size_t)rr * d.ldo + c0] = val;
                if (d.outH) d.outH[(size_t)rr * d.ldo + c0] = (half_t)(val + bval);
            }
        }
    }
}

// ---------------------------------------------------------------------------
// Fused main kernel: block (st, bb) computes scores & W2 for 64 s-values x one batch,
// then softmax over n + dot in-block, writing out[bg][s] directly.
// AstackP rows: 2s = Qk_s, 2s+1 = Wv2_s (768 rows).  Tile: 128 rows x 224 cols, K=2048.
// grid (5, nB), block 256 (4 waves, 2x2; per-wave 64 x 112).
__global__ __launch_bounds__(256) void k_fused(const half_t* __restrict__ AstackP, const half_t* __restrict__ featT,
                                               const float* __restrict__ base, const float* __restrict__ ubv,
                                               float* __restrict__ out, int b0) {
    __shared__ __attribute__((aligned(16))) half_t lsA[3][128 * 32];
    __shared__ __attribute__((aligned(16))) half_t lsB[3][256 * 32];
    __shared__ float lsE[2][64][4];
    int t = threadIdx.x;
    int wid = t >> 6, lane = t & 63;
    int st = blockIdx.x, bb = blockIdx.y;
    int wr = wid >> 1, wc = wid & 1;
    int g = lane >> 4, l15 = lane & 15;
    const int r_ = t >> 2;
    const int gsrc = ((t & 3) ^ ((t >> 3) & 3)) * 8;
    const half_t* pA  = AstackP + ((size_t)st * 128 + r_) * C_ + gsrc;
    const half_t* pA2 = pA + (size_t)64 * C_;
    const half_t* pB  = featT + ((size_t)bb * NP + r_) * C_ + gsrc;   // stages 256 rows (32 over-stage)
    const half_t* pB2 = pB + (size_t)64 * C_;
    const half_t* pB3 = pB + (size_t)128 * C_;
    const half_t* pB4 = pB + (size_t)192 * C_;
    const int lo = t * 8;
    const int xsw = ((l15 >> 1) & 3) * 8;
    f32x4 acc[4][7] = {};

#define FSTAGE(slot, kc)                             \
    do {                                             \
        gload16(pA + (kc), &lsA[slot][lo]);          \
        gload16(pA2 + (kc), &lsA[slot][lo + 2048]);  \
        gload16(pB + (kc), &lsB[slot][lo]);          \
        gload16(pB2 + (kc), &lsB[slot][lo + 2048]);  \
        gload16(pB3 + (kc), &lsB[slot][lo + 4096]);  \
        gload16(pB4 + (kc), &lsB[slot][lo + 6144]);  \
    } while (0)

    FSTAGE(0, 0);
    FSTAGE(1, 32);
    int cur = 0, nxt = 2;
    for (int tk = 0; tk < 64; ++tk) {
        if (tk == 63) asm volatile("s_waitcnt vmcnt(0)" ::: "memory");
        else          asm volatile("s_waitcnt vmcnt(6)" ::: "memory");
        __builtin_amdgcn_s_barrier();
        __builtin_amdgcn_sched_barrier(0);
        f16x8 af[4], bf[7];
#pragma unroll
        for (int i = 0; i < 4; ++i) af[i] = *(const f16x8*)&lsA[cur][(wr * 64 + i * 16 + l15) * 32 + ((g * 8) ^ xsw)];
#pragma unroll
        for (int j = 0; j < 7; ++j) bf[j] = *(const f16x8*)&lsB[cur][(wc * 112 + j * 16 + l15) * 32 + ((g * 8) ^ xsw)];
        if (tk + 2 < 64) FSTAGE(nxt, (tk + 2) * 32);
#pragma unroll
        for (int i = 0; i < 4; ++i)
#pragma unroll
            for (int j = 0; j < 7; ++j)
                acc[i][j] = __builtin_amdgcn_mfma_f32_16x16x32_f16(af[i], bf[j], acc[i][j], 0, 0, 0);
        cur = (cur == 2) ? 0 : cur + 1;
        nxt = (nxt == 2) ? 0 : nxt + 1;
    }
#undef FSTAGE

    // ---- epilogue: per s-row softmax over n + dot with W2 ----
    // lane's acc[i][j][qq]: row = wr*64+i*16+g*4+qq (even=score row 2s, odd=W2 row 2s+1),
    //                       col = wc*112+j*16+l15
#pragma unroll
    for (int i = 0; i < 4; ++i) {
#pragma unroll
        for (int pair = 0; pair < 2; ++pair) {
            float m = -3.0e38f;
#pragma unroll
            for (int j = 0; j < 7; ++j) {
                int col = wc * 112 + j * 16 + l15;
                if (col < N_) m = fmaxf(m, acc[i][j][2 * pair]);
            }
#pragma unroll
            for (int off = 1; off < 16; off <<= 1) m = fmaxf(m, __shfl_xor(m, off));
            float ls = 0.f, dt = 0.f;
#pragma unroll
            for (int j = 0; j < 7; ++j) {
                int col = wc * 112 + j * 16 + l15;
                if (col < N_) {
                    float p = __expf(acc[i][j][2 * pair] - m);
                    ls += p;
                    dt += p * acc[i][j][2 * pair + 1];
                }
            }
#pragma unroll
            for (int off = 1; off < 16; off <<= 1) { ls += __shfl_xor(ls, off); dt += __shfl_xor(dt, off); }
            if (l15 == 0) {
                int pr = wr * 32 + i * 8 + g * 2 + pair;
                lsE[wc][pr][0] = m; lsE[wc][pr][1] = ls; lsE[wc][pr][2] = dt;
            }
        }
    }
    __syncthreads();
    if (t < 64) {
        float m0 = lsE[0][t][0], l0 = lsE[0][t][1], dv0 = lsE[0][t][2];
        float m1 = lsE[1][t][0], l1 = lsE[1][t][1], dv1 = lsE[1][t][2];
        float M = fmaxf(m0, m1);
        float e0 = __expf(m0 - M), e1 = __expf(m1 - M);
        float L = l0 * e0 + l1 * e1, D = dv0 * e0 + dv1 * e1;
        int s = st * 64 + t;
        if (s < S_) {
            int bg = b0 + bb;
            out[(size_t)bg * S_ + s] = base[(size_t)bg * S_ + s] + ubv[s] + D / L;
        }
    }
}

// ---------------------------------------------------------------------------
// feat [nB][2048][196] f32 -> featT [(bb*224 + n)][2048] f16 (n zero-padded to 224)
// PLUS fused pool partials: poolp[(nT*B_ + bb)*C_ + c] = sum over this block's n of feat[b][c][n]
// grid (4 nT, 32 cT, nB), block 256
__global__ __launch_bounds__(256) void k_transf(const float* __restrict__ feat, half_t* __restrict__ featT,
                                                float* __restrict__ poolp) {
    __shared__ __attribute__((aligned(16))) half_t lsT[64][72];
    __shared__ float poolLs[64];
    int nT = blockIdx.x, cT = blockIdx.y, bb = blockIdx.z;
    int n0 = nT * 64, c0 = cT * 64;
    const float* fb = feat + (size_t)bb * C_ * N_;
    int t = threadIdx.x;
#pragma unroll
    for (int i = 0; i < 4; ++i) {
        int Q = t + 256 * i;
        int cq = Q >> 5, nq = Q & 31;
        int cc = 2 * cq, nn = 2 * nq;
        int n = n0 + nn;
        float2 va = {0, 0}, vb = {0, 0};
        if (n < N_) {
            const float* p0 = fb + (size_t)(c0 + cc) * N_ + n;
            va = *(const float2*)p0;
            vb = *(const float2*)(p0 + N_);
        }
        f16x2 w0; w0[0] = (half_t)va.x; w0[1] = (half_t)vb.x;
        f16x2 w1; w1[0] = (half_t)va.y; w1[1] = (half_t)vb.y;
        *(f16x2*)&lsT[nn][cc]     = w0;   // lsT[n][c]
        *(f16x2*)&lsT[nn + 1][cc] = w1;
        float sA = va.x + va.y, sB = vb.x + vb.y;
        for (int off = 16; off; off >>= 1) { sA += __shfl_xor(sA, off); sB += __shfl_xor(sB, off); }
        if ((t & 31) == 0) { poolLs[cc] = sA; poolLs[cc + 1] = sB; }
    }
    __syncthreads();
    int nl = t >> 2, ch = t & 3;
    int n = n0 + nl;
    if (n < NP) {   // rows [224,256) of nT=3 must NOT spill into the next batch's tile
        f16x8 v0 = *(const f16x8*)&lsT[nl][ch * 16];
        f16x8 v1 = *(const f16x8*)&lsT[nl][ch * 16 + 8];
        half_t* po = featT + ((size_t)bb * NP + n) * C_ + c0 + ch * 16;
        *(f16x8*)po = v0;
        *(f16x8*)(po + 8) = v1;
    }
    if (t < 64) poolp[((size_t)nT * B_ + bb) * C_ + c0 + t] = poolLs[t];
}

// ---------------------------------------------------------------------------
// base[b][s] = sum_c (mean_pool[b][c] + bo[c]) * V[s][c].  grid (4 sc, nB b), block 256
__global__ __launch_bounds__(256) void k_poolv(const float* __restrict__ poolp, const float* __restrict__ bo,
                                               const float* __restrict__ V, float* __restrict__ base) {
    int sc = blockIdx.x, b = blockIdx.y;
    __shared__ float w[C_];
    int t = threadIdx.x;
    for (int i = t; i < C_; i += 256) {
        float s = poolp[(size_t)b * C_ + i] + poolp[((size_t)B_ + b) * C_ + i] +
                  poolp[((size_t)2 * B_ + b) * C_ + i] + poolp[((size_t)3 * B_ + b) * C_ + i];
        w[i] = s * (1.0f / 196.0f) + bo[i];
    }
    __syncthreads();
    int wid = t >> 6, lane = t & 63;
    for (int s = sc * 78 + wid; s < sc * 78 + 78; s += 4) {
        const float* vr = V + (size_t)s * C_;
        float acc = 0;
#pragma unroll
        for (int i = 0; i < 32; ++i) acc += w[lane + 64 * i] * vr[lane + 64 * i];
        for (int off = 32; off; off >>= 1) acc += __shfl_xor(acc, off);
        if (lane == 0) base[(size_t)b * S_ + s] = acc;
    }
}

// ---------------------------------------------------------------------------
// ubv[s] = sum_m U[s][m]*bv[m].  grid 78, block 256 (wave per s)
__global__ __launch_bounds__(256) void k_ubv(const float* __restrict__ U, const float* __restrict__ bv,
                                             float* __restrict__ ubv) {
    int s = blockIdx.x * 4 + (threadIdx.x >> 6);
    int lane = threadIdx.x & 63;
    if (s >= S_) return;
    const float* ur = U + (size_t)s * M_;
    float acc = 0;
#pragma unroll
    for (int i = 0; i < 16; ++i) acc += ur[lane + 64 * i] * bv[lane + 64 * i];
    for (int off = 32; off; off >>= 1) acc += __shfl_xor(acc, off);
    if (lane == 0) ubv[s] = acc;
}

// ---------------------------------------------------------------------------
extern "C" void kernel_launch(void* const* d_in, const int* in_sizes, int n_in,
                              void* d_out, int out_size, void* d_ws, size_t ws_size,
                              hipStream_t stream) {
    const float* feat = (const float*)d_in[0];
    const float* att  = (const float*)d_in[1];
    const float* Wq   = (const float*)d_in[2];
    const float* bq   = (const float*)d_in[3];
    const float* Wk   = (const float*)d_in[4];
    /* bk = d_in[5] — per-s constant over n in scores: softmax-invariant, dropped */
    const float* Wv   = (const float*)d_in[6];
    const float* bv   = (const float*)d_in[7];
    const float* Wo   = (const float*)d_in[8];
    const float* bo   = (const float*)d_in[9];
    const float* V    = (const float*)d_in[10];
    float* out = (float*)d_out;

    auto AL = [](size_t x) { return (x + 255) & ~(size_t)255; };
    const size_t szAstk = (size_t)768 * C_ * 2;       // pair-interleaved [2s | 2s+1]
    const size_t szQh   = (size_t)SP * M_ * 2;
    const size_t szVh   = (size_t)SP * C_ * 2;
    const size_t szUf   = (size_t)SP * M_ * 4;
    const size_t szUh   = (size_t)SP * M_ * 2;
    const size_t szWT   = (size_t)C_ * M_ * 2;
    const size_t szAtth = (size_t)SP * LP * 2;
    const size_t szWqh  = (size_t)M_ * LP * 2;
    const size_t szPoolp = (size_t)4 * B_ * C_ * 4;
    const size_t szBase = (size_t)B_ * S_ * 4;
    const size_t szUbv  = (size_t)S_ * 4;
    size_t fixed = AL(szAstk) + AL(szQh) + AL(szVh) + AL(szUf) + AL(szUh) + 3 * AL(szWT) +
                   AL(szAtth) + AL(szWqh) + AL(szPoolp) + AL(szBase) + AL(szUbv);

    int nsplit = 1;
    while (nsplit < 32) {
        size_t nB = B_ / nsplit;
        size_t need = fixed + AL(nB * NP * C_ * 2 + 131072);  // +128KB over-stage slack
        if (need <= ws_size) break;
        nsplit *= 2;
    }
    int nB = B_ / nsplit;

    char* p = (char*)d_ws;
    half_t* AstackP = (half_t*)p; p += AL(szAstk);
    half_t* qh     = (half_t*)p; p += AL(szQh);
    half_t* Vh     = (half_t*)p; p += AL(szVh);
    float*  Uf     = (float*)p;  p += AL(szUf);
    half_t* Uh     = (half_t*)p; p += AL(szUh);
    half_t* WkT    = (half_t*)p; p += AL(szWT);
    half_t* WoT    = (half_t*)p; p += AL(szWT);
    half_t* WvT    = (half_t*)p; p += AL(szWT);
    half_t* atth   = (half_t*)p; p += AL(szAtth);
    half_t* wqh    = (half_t*)p; p += AL(szWqh);
    float*  poolp  = (float*)p;  p += AL(szPoolp);
    float*  base   = (float*)p;  p += AL(szBase);
    float*  ubv    = (float*)p;  p += AL(szUbv);
    half_t* featT  = (half_t*)p;

    // ---- batch-independent precompute ----
    k_convert<<<dim3(768, 1, 3), 256, 0, stream>>>(att, Wq, V, atth, wqh, Vh);
    k_transp3<<<dim3(32, 32, 3), 256, 0, stream>>>(Wk, Wo, Wv, WkT, WoT, WvT);
    // prepA: z0 q = att@Wq.T + bq (f16);  z1 U = V@Wo (f32 + f16)
    {
        GDesc dq{atth, wqh, nullptr, qh, bq, LP, M_, 1, 0};
        GDesc dU{Vh, WoT, Uf, Uh, nullptr, C_, M_, 1, 0};
        k_prep<<<dim3(8, 3, 2), 256, 0, stream>>>(dq, dU);
    }
    k_ubv<<<dim3(78), 256, 0, stream>>>(Uf, bv, ubv);
    // prepB: z0 Qk = q@Wk -> rows 2s;  z1 Wv2 = U@Wv -> rows 2s+1
    {
        GDesc dk{qh, WkT, nullptr, AstackP, nullptr, M_, C_, 2, 0};
        GDesc dv{Uh, WvT, nullptr, AstackP, nullptr, M_, C_, 2, 1};
        k_prep<<<dim3(16, 3, 2), 256, 0, stream>>>(dk, dv);
    }

    // ---- main per-batch-split pipeline ----
    for (int h = 0; h < nsplit; ++h) {
        const float* fh = feat + (size_t)h * nB * C_ * N_;
        k_transf<<<dim3(4, 32, nB), 256, 0, stream>>>(fh, featT, poolp);
        k_poolv<<<dim3(4, nB), 256, 0, stream>>>(poolp, bo, V, base + (size_t)h * nB * S_);
        k_fused<<<dim3(5, nB), 256, 0, stream>>>(AstackP, featT, base, ubv, out, h * nB);
    }
}